// Round 11
// baseline (66.585 us; speedup 1.0000x reference)
//
#include <hip/hip_runtime.h>

#define N_ROWS 128
#define IN_DIM 1024
#define OUT_DIM 1024

// out[n,o] = max_k(w[o,k] + x[n,k]) + bias[o]   (tropical matmul)
//
// R11 = R10 + (a) packed-fp32 inner loop + (b) global_load_lds staging.
// (a) v_pk_add_f32: 4-k step was 4 add + 2 max3 = 6 VALU; now
//     2 pk_add + 2 max3 = 4 -> VALU floor 6144 -> 4096 cyc/SIMD
//     (2.56 -> 1.71 us). ext_vector_type(2) add lowers to pk_add on
//     gfx90a+; scalarization fallback = status quo (no downside).
// (b) w-panel staged via __builtin_amdgcn_global_load_lds(16B): kills
//     16 dwordx4->VGPR + 16 ds_write_b128 per thread (~1024 cyc/CU of
//     LDS write pipe + issue slots). Layout already wave-uniform-base
//     + lane*16 (idx = tid + i*256, linear) as the HW requires.
// Everything else identical to R10 (verified): 512 blocks (8bn x 64bo,
// idx%8==bo%8 same-XCD), 256 thr, h-split wave (o-rows h*8..+7, k-slice
// g in 0..31, 8 f4/row), w-in-LDS-once, x-in-regs, vectorized scratch
// epilogue, 2 blocks/CU = 8 waves/CU.
// Ledger: kernel ~6.1 us = main(max(LDS 2.56, VALU 2.56)) + prologue
// + epilogue&latency. Predicted: kernel -> ~4.8, dur 66.3 -> ~65.

typedef float f32x2 __attribute__((ext_vector_type(2)));

__global__ __launch_bounds__(256, 2)
void tropical_linear_kernel(const float* __restrict__ x,
                            const float* __restrict__ w,
                            const float* __restrict__ bias,
                            float* __restrict__ out) {
    // 64 KB: w-panel (16 o-rows x 256 f4); reused post-barrier as 4
    // per-wave scratchpads of 64 lanes x 36 words (9216 B each).
    __shared__ float lds_raw[16384];
    float4* wlds = (float4*)lds_raw;

    const int tid  = threadIdx.x;
    const int wid  = tid >> 6;       // wave 0..3 -> n-rows wid*4..+3
    const int lane = tid & 63;
    const int h    = lane >> 5;      // o-half: rows h*8..h*8+7
    const int g    = lane & 31;      // k-slice owner: f4s {t*32+g}

    const int bn = blockIdx.x >> 6;  // 8 n-blocks
    const int bo = blockIdx.x & 63;  // 64 o-blocks (idx%8==bo%8 -> same XCD)
    const int n0 = bn * 16;
    const int o0 = bo * 16;

    // ---- stage w panel: 4096 f4 via async global->LDS DMA (16B/lane,
    //      no VGPR roundtrip, no ds_write pipe traffic) ----
    const float4* __restrict__ wg = (const float4*)w + (size_t)o0 * 256;
#pragma unroll
    for (int i = 0; i < 16; ++i) {
        const int idx = tid + i * 256;   // linear: wave-base + lane*16B
        __builtin_amdgcn_global_load_lds(
            (const __attribute__((address_space(1))) void*)(wg + idx),
            (__attribute__((address_space(3))) void*)(wlds + idx),
            16, 0, 0);
    }

    // ---- x -> registers: 4 rows x 8 f4 per lane (halves duplicate the
    //      same addresses in-instruction -> no extra HBM bytes) ----
    const float4* __restrict__ xg =
        (const float4*)x + (size_t)(n0 + wid * 4) * 256 + g;
    float4 xr[4][8];
#pragma unroll
    for (int j = 0; j < 4; ++j)
#pragma unroll
        for (int t = 0; t < 8; ++t)
            xr[j][t] = xg[j * 256 + t * 32];

    float acc[4][8];
#pragma unroll
    for (int j = 0; j < 4; ++j)
#pragma unroll
        for (int ol = 0; ol < 8; ++ol) acc[j][ol] = -3.4e38f;

    __syncthreads();   // drains the LDS-DMA (vmcnt) + syncs waves

    // ---- main loop: 8 o-rows per half; packed-fp32 inner ----
    const float4* __restrict__ wlh = wlds + (size_t)(h * 8) * 256 + g;
#pragma unroll
    for (int ol = 0; ol < 8; ++ol) {
        float4 wv[8];
#pragma unroll
        for (int t = 0; t < 8; ++t) wv[t] = wlh[ol * 256 + t * 32];
#pragma unroll
        for (int j = 0; j < 4; ++j)
#pragma unroll
            for (int t = 0; t < 8; ++t) {
                const float4 xv = xr[j][t];
                const f32x2 a = *(const f32x2*)&wv[t].x + *(const f32x2*)&xv.x;  // v_pk_add_f32
                const f32x2 b = *(const f32x2*)&wv[t].z + *(const f32x2*)&xv.z;  // v_pk_add_f32
                const float m = fmaxf(fmaxf(a.x, a.y), b.x);        // v_max3
                acc[j][ol] = fmaxf(fmaxf(m, b.y), acc[j][ol]);      // v_max3
            }
    }

    // ---- k-reduce: 32 partials/output via padded per-wave scratch ----
    __syncthreads();   // all waves done reading the panel; safe to reuse
    float* scr = lds_raw + wid * (64 * 36);
    float4* scr4 = (float4*)scr;     // lane row = 9 f4 (36 words, 16B-aligned)

    // write: lane's 32 values (v = j*8 + ol) as 8 b128; banks native
#pragma unroll
    for (int j = 0; j < 4; ++j) {
        scr4[lane * 9 + j * 2 + 0] =
            make_float4(acc[j][0], acc[j][1], acc[j][2], acc[j][3]);
        scr4[lane * 9 + j * 2 + 1] =
            make_float4(acc[j][4], acc[j][5], acc[j][6], acc[j][7]);
    }
    // same-wave LDS RAW: in-order LDS pipe + compiler lgkmcnt (R9/R10-validated)

    // read+fold: lane p owns output (j=p>>4, o=p&15); its 32 partials sit
    // at rows (h(o)*32 + s), word v = j*8 + (o&7). Banks (4s+v)%32: 2-way.
    {
        const int jj = lane >> 4;
        const int oo = lane & 15;
        const int hh = oo >> 3;
        const int vv = jj * 8 + (oo & 7);
        const float* base = scr + (size_t)(hh * 32) * 36 + vv;
        float m0 = -3.4e38f, m1 = -3.4e38f, m2 = -3.4e38f, m3 = -3.4e38f;
#pragma unroll
        for (int s = 0; s < 32; s += 4) {
            m0 = fmaxf(m0, base[(s + 0) * 36]);
            m1 = fmaxf(m1, base[(s + 1) * 36]);
            m2 = fmaxf(m2, base[(s + 2) * 36]);
            m3 = fmaxf(m3, base[(s + 3) * 36]);
        }
        const float m = fmaxf(fmaxf(m0, m1), fmaxf(m2, m3));
        const int o = o0 + oo;
        out[(size_t)(n0 + wid * 4 + jj) * OUT_DIM + o] = m + bias[o];
    }
}

extern "C" void kernel_launch(void* const* d_in, const int* in_sizes, int n_in,
                              void* d_out, int out_size, void* d_ws, size_t ws_size,
                              hipStream_t stream) {
    const float* x    = (const float*)d_in[0];   // [128,1024]
    const float* w    = (const float*)d_in[1];   // [1024,1024]
    const float* bias = (const float*)d_in[2];   // [1024]
    float* out = (float*)d_out;                  // [128,1024]

    dim3 grid(512);
    dim3 block(256);
    hipLaunchKernelGGL(tropical_linear_kernel, grid, block, 0, stream,
                       x, w, bias, out);
}

// Round 14
// 65.890 us; speedup vs baseline: 1.0105x; 1.0105x over previous
//
#include <hip/hip_runtime.h>

#define N_ROWS 128
#define IN_DIM 1024
#define OUT_DIM 1024

// out[n,o] = max_k(w[o,k] + x[n,k]) + bias[o]   (tropical matmul)
//
// R14 = R12 RESUBMIT #2 (rounds 12 & 13 were container-level infra
// failures; round 0 showed the same failure with a known-good kernel.
// All R12 components individually HW-validated: global_load_lds linear
// dest (R11), 66560 B LDS + bounds(256,2) (R9), index ranges checked.
// No design change on zero evidence.)
//
// R12: double the w-reuse per LDS read (j: 4 -> 8 x-rows per ds_read_b128).
// Null-chain: R10 (epilogue -62% LDS) null -> epilogue off critical path;
// R11a (pk_add) null -> VALU not binding; R11b (DMA staging) null ->
// LDS write BW unchanged / overlapped. Largest critical-path item left:
// main-loop LDS reads 512 b128/CU = 2.56 us, set by reuse j.
//   Tile: 32n x 8o; grid 4 bn x 128 bo = 512 blocks = 2/CU (8 waves/CU).
//   Wave wid owns n-rows n0+wid*8..+7; lane owns k-f4s {t*64+lane}.
//   xr[8][4] = 128 VGPR, acc[8][8] = 64, wv 16 -> ~225 total: 2/SIMD ok.
//   w-panel 8 rows = 32 KB staged via global_load_lds (8 f4/thread).
//   Main loop: per o (x8): 4 ds_read_b128 + 8j x 4t x (2 pk_add + 2 max3).
//   Per-CU main LDS = 256 b128 = 1.28 us (was 2.56); staging halves too.
//   Epilogue: R9-style b32 transpose scratch (pitch 65, 2-way free),
//   64-wide reduce, proven off-critical-path (R10 null).
// LDS = max(32 KB panel, 65 KB scratch) = 66560 B -> 2 blocks = 133 KB ok.
// XCD: idx%8 == bo%8 -> the blocks sharing a w-panel share an XCD.
// Predicted: kernel 6.1 -> ~4.6-5.0 us; dur 66.3 -> 64.8-65.3.
// Pre-commit: null => latency-floored, declare roofline next round.

typedef float f32x2 __attribute__((ext_vector_type(2)));

__global__ __launch_bounds__(256, 2)
void tropical_linear_kernel(const float* __restrict__ x,
                            const float* __restrict__ w,
                            const float* __restrict__ bias,
                            float* __restrict__ out) {
    // 66560 B: w-panel (8 o-rows x 256 f4 = 32 KB) first, then reused as
    // 4 per-wave reduction scratchpads of 64x65 floats (16640 B each).
    __shared__ float lds_raw[4 * 64 * 65];
    float4* wlds = (float4*)lds_raw;

    const int tid  = threadIdx.x;
    const int wid  = tid >> 6;       // wave 0..3 -> n-rows wid*8..+7
    const int lane = tid & 63;       // k-slice owner: f4s {t*64+lane}

    const int bn = blockIdx.x >> 7;  // 4 n-blocks
    const int bo = blockIdx.x & 127; // 128 o-blocks (idx%8==bo%8 -> same XCD)
    const int n0 = bn * 32;
    const int o0 = bo * 8;

    // ---- stage w panel: 2048 f4 via global->LDS DMA, 8 f4/thread ----
    const float4* __restrict__ wg = (const float4*)w + (size_t)o0 * 256;
#pragma unroll
    for (int i = 0; i < 8; ++i) {
        const int idx = tid + i * 256;   // linear: wave-base + lane*16B
        __builtin_amdgcn_global_load_lds(
            (const __attribute__((address_space(1))) void*)(wg + idx),
            (__attribute__((address_space(3))) void*)(wlds + idx),
            16, 0, 0);
    }

    // ---- x -> registers: 8 rows x 4 f4 per lane, coalesced ----
    const float4* __restrict__ xg =
        (const float4*)x + (size_t)(n0 + wid * 8) * 256 + lane;
    float4 xr[8][4];
#pragma unroll
    for (int j = 0; j < 8; ++j)
#pragma unroll
        for (int t = 0; t < 4; ++t)
            xr[j][t] = xg[j * 256 + t * 64];

    float acc[8][8];
#pragma unroll
    for (int j = 0; j < 8; ++j)
#pragma unroll
        for (int o = 0; o < 8; ++o) acc[j][o] = -3.4e38f;

    __syncthreads();   // drains LDS-DMA + syncs waves

    // ---- main loop: 8 o-rows; each w-read feeds 8 x-rows ----
    const float4* __restrict__ wl = wlds + lane;
#pragma unroll
    for (int o = 0; o < 8; ++o) {
        float4 wv[4];
#pragma unroll
        for (int t = 0; t < 4; ++t) wv[t] = wl[o * 256 + t * 64];
#pragma unroll
        for (int j = 0; j < 8; ++j)
#pragma unroll
            for (int t = 0; t < 4; ++t) {
                const float4 xv = xr[j][t];
                const f32x2 a = *(const f32x2*)&wv[t].x + *(const f32x2*)&xv.x;  // v_pk_add_f32
                const f32x2 b = *(const f32x2*)&wv[t].z + *(const f32x2*)&xv.z;  // v_pk_add_f32
                const float m = fmaxf(fmaxf(a.x, a.y), b.x);    // v_max3
                acc[j][o] = fmaxf(fmaxf(m, b.y), acc[j][o]);    // v_max3
            }
    }

    // ---- k-reduce: 64 partials/output via per-wave transposed scratch ----
    __syncthreads();   // all waves done reading the panel; safe to reuse
    float* scr = lds_raw + wid * (64 * 65);

    // write: lane stores its 64 partials at scr[p*65 + lane], p=j*8+o
    // banks: (p*65+lane)%32 = (p+lane)%32 -> 2-way across 64 lanes, free
#pragma unroll
    for (int j = 0; j < 8; ++j)
#pragma unroll
        for (int o = 0; o < 8; ++o)
            scr[(j * 8 + o) * 65 + lane] = acc[j][o];
    // same-wave LDS RAW: in-order LDS pipe + compiler lgkmcnt (R9-validated)

    // read+fold: lane p owns output (j=p>>3, o=p&7); partials at
    // scr[p*65 + l], l=0..63 (consecutive words -> 2-way, free);
    // 4 independent fold chains for ILP.
    {
        const float* base = scr + lane * 65;
        float m0 = -3.4e38f, m1 = -3.4e38f, m2 = -3.4e38f, m3 = -3.4e38f;
#pragma unroll
        for (int l = 0; l < 64; l += 4) {
            m0 = fmaxf(m0, base[l + 0]);
            m1 = fmaxf(m1, base[l + 1]);
            m2 = fmaxf(m2, base[l + 2]);
            m3 = fmaxf(m3, base[l + 3]);
        }
        const float m = fmaxf(fmaxf(m0, m1), fmaxf(m2, m3));
        const int jj = lane >> 3;
        const int oo = lane & 7;
        const int o  = o0 + oo;
        out[(size_t)(n0 + wid * 8 + jj) * OUT_DIM + o] = m + bias[o];
    }
}

extern "C" void kernel_launch(void* const* d_in, const int* in_sizes, int n_in,
                              void* d_out, int out_size, void* d_ws, size_t ws_size,
                              hipStream_t stream) {
    const float* x    = (const float*)d_in[0];   // [128,1024]
    const float* w    = (const float*)d_in[1];   // [1024,1024]
    const float* bias = (const float*)d_in[2];   // [1024]
    float* out = (float*)d_out;                  // [128,1024]

    dim3 grid(512);
    dim3 block(256);
    hipLaunchKernelGGL(tropical_linear_kernel, grid, block, 0, stream,
                       x, w, bias, out);
}